// Round 1
// baseline (177.648 us; speedup 1.0000x reference)
//
#include <hip/hip_runtime.h>

#define B_ 8
#define T_ 2048
#define C_ 768
#define H_ 64

typedef __bf16 bf16x8 __attribute__((ext_vector_type(8)));
typedef unsigned short ushort8 __attribute__((ext_vector_type(8)));
typedef float f32x4 __attribute__((ext_vector_type(4)));

static __device__ __forceinline__ unsigned short f32_to_bf16(float f) {
  unsigned int u = __float_as_uint(f);
  u += 0x7FFFu + ((u >> 16) & 1u);
  return (unsigned short)(u >> 16);
}

static __device__ __forceinline__ f32x4 mfma16(ushort8 a, ushort8 b, f32x4 c) {
  return __builtin_amdgcn_mfma_f32_16x16x32_bf16(
      __builtin_bit_cast(bf16x8, a), __builtin_bit_cast(bf16x8, b), c, 0, 0, 0);
}

// ---------------- Kernel 0: W -> Wt (bf16, transposed [3][64][768], Wq pre-scaled) ---
__global__ void prep_w_kernel(const float* __restrict__ Wk, const float* __restrict__ Wq,
                              const float* __restrict__ Wv, unsigned short* __restrict__ Wt) {
  int idx = blockIdx.x * 256 + threadIdx.x;
  if (idx >= 3 * C_ * H_) return;
  int p = idx / (C_ * H_);
  int rem = idx - p * (C_ * H_);
  int k = rem >> 6;   // row in W [768][64]
  int n = rem & 63;   // col
  const float* W = (p == 0) ? Wk : (p == 1) ? Wq : Wv;
  float v = W[rem];
  if (p == 1) v *= 0.125f;  // fold head_size^-0.5 into Q (exact power of 2)
  Wt[p * (H_ * C_) + n * C_ + k] = f32_to_bf16(v);
}

// ---------------- Kernel 1: projections x@Wk, x@Wq, x@Wv via MFMA --------------------
// grid = (B*T)/64 blocks, 256 threads (4 waves); wave w handles rows [blk*64+w*16, +16)
__global__ __launch_bounds__(256) void proj_kernel(
    const float* __restrict__ x, const unsigned short* __restrict__ Wt,
    unsigned short* __restrict__ Qb, unsigned short* __restrict__ Kb,
    unsigned short* __restrict__ Vt) {
  const int tid = threadIdx.x;
  const int wave = tid >> 6;
  const int lane = tid & 63;
  const int lo = lane & 15, hi = lane >> 4;
  const int row0 = blockIdx.x * 64 + wave * 16;

  f32x4 acc[3][4];
#pragma unroll
  for (int p = 0; p < 3; ++p)
#pragma unroll
    for (int nt = 0; nt < 4; ++nt) acc[p][nt] = (f32x4){0.f, 0.f, 0.f, 0.f};

  const float* xrow = x + (size_t)(row0 + lo) * C_;
  for (int kc = 0; kc < C_; kc += 32) {
    const int ko = kc + hi * 8;
    float4 a0 = *(const float4*)(xrow + ko);
    float4 a1 = *(const float4*)(xrow + ko + 4);
    ushort8 a;
    a[0] = f32_to_bf16(a0.x); a[1] = f32_to_bf16(a0.y);
    a[2] = f32_to_bf16(a0.z); a[3] = f32_to_bf16(a0.w);
    a[4] = f32_to_bf16(a1.x); a[5] = f32_to_bf16(a1.y);
    a[6] = f32_to_bf16(a1.z); a[7] = f32_to_bf16(a1.w);
#pragma unroll
    for (int p = 0; p < 3; ++p) {
#pragma unroll
      for (int nt = 0; nt < 4; ++nt) {
        ushort8 bfr = *(const ushort8*)(Wt + p * (H_ * C_) + (nt * 16 + lo) * C_ + ko);
        acc[p][nt] = mfma16(a, bfr, acc[p][nt]);
      }
    }
  }

  // epilogue: D-layout row=(hi*4+r), col=(nt*16+lo)
#pragma unroll
  for (int nt = 0; nt < 4; ++nt) {
#pragma unroll
    for (int r = 0; r < 4; ++r) {
      const int rg = row0 + hi * 4 + r;     // global row in [0, B*T)
      const int n = nt * 16 + lo;
      Kb[rg * H_ + n] = f32_to_bf16(acc[0][nt][r]);
      Qb[rg * H_ + n] = f32_to_bf16(acc[1][nt][r]);
      const int b = rg >> 11;               // T = 2048
      const int t = rg & (T_ - 1);
      Vt[((b * H_ + n) << 11) + t] = f32_to_bf16(acc[2][nt][r]);
    }
  }
}

// ---------------- Kernel 2: causal flash attention -----------------------------------
// grid = (T/64, B), 256 threads (4 waves); wave w owns Q rows [qt*64+w*16, +16)
__global__ __launch_bounds__(256) void attn_kernel(
    const unsigned short* __restrict__ Qb, const unsigned short* __restrict__ Kb,
    const unsigned short* __restrict__ Vt, float* __restrict__ out) {
  __shared__ unsigned short p_lds[4][16 * 72];  // per-wave P tile, padded stride 72
  const int tid = threadIdx.x;
  const int wave = tid >> 6;
  const int lane = tid & 63;
  const int lo = lane & 15, hi = lane >> 4;
  const int b = blockIdx.y;
  const int qt = blockIdx.x;
  const int i0 = qt * 64 + wave * 16;  // wave's first Q row within batch
  const size_t bt = (size_t)b * T_;

  // Q fragments (pre-scaled by 0.125 at projection time)
  ushort8 qf[2];
  qf[0] = *(const ushort8*)(Qb + (bt + i0 + lo) * H_ + hi * 8);
  qf[1] = *(const ushort8*)(Qb + (bt + i0 + lo) * H_ + 32 + hi * 8);

  f32x4 o[4];
#pragma unroll
  for (int nt = 0; nt < 4; ++nt) o[nt] = (f32x4){0.f, 0.f, 0.f, 0.f};
  float m[4] = {-1e30f, -1e30f, -1e30f, -1e30f};
  float lsum[4] = {0.f, 0.f, 0.f, 0.f};

  for (int jt = 0; jt <= qt; ++jt) {
    const int j0 = jt * 64;
    // S = Q K^T  (B-fragment = rows of K, d contiguous)
    f32x4 s[4];
#pragma unroll
    for (int nt = 0; nt < 4; ++nt) s[nt] = (f32x4){0.f, 0.f, 0.f, 0.f};
#pragma unroll
    for (int c = 0; c < 2; ++c) {
#pragma unroll
      for (int nt = 0; nt < 4; ++nt) {
        ushort8 kf = *(const ushort8*)(Kb + (bt + j0 + nt * 16 + lo) * H_ + c * 32 + hi * 8);
        s[nt] = mfma16(qf[c], kf, s[nt]);
      }
    }
    // causal mask on diagonal tile: j_local > i_local => -inf
    if (jt == qt) {
#pragma unroll
      for (int nt = 0; nt < 4; ++nt)
#pragma unroll
        for (int r = 0; r < 4; ++r)
          if (nt * 16 + lo > wave * 16 + hi * 4 + r) s[nt][r] = -1e30f;
    }
    // row max over 64 cols: 4 frags then shfl_xor over the 16-lane col group
    float mnew[4], scl[4];
#pragma unroll
    for (int r = 0; r < 4; ++r) {
      float t = fmaxf(fmaxf(s[0][r], s[1][r]), fmaxf(s[2][r], s[3][r]));
      t = fmaxf(t, __shfl_xor(t, 1));
      t = fmaxf(t, __shfl_xor(t, 2));
      t = fmaxf(t, __shfl_xor(t, 4));
      t = fmaxf(t, __shfl_xor(t, 8));
      mnew[r] = fmaxf(m[r], t);
      scl[r] = __expf(m[r] - mnew[r]);
      m[r] = mnew[r];
    }
    // p = exp(s - mnew); row sums
    float tsum[4] = {0.f, 0.f, 0.f, 0.f};
#pragma unroll
    for (int nt = 0; nt < 4; ++nt)
#pragma unroll
      for (int r = 0; r < 4; ++r) {
        float p = __expf(s[nt][r] - mnew[r]);
        s[nt][r] = p;
        tsum[r] += p;
      }
#pragma unroll
    for (int r = 0; r < 4; ++r) {
      float t = tsum[r];
      t += __shfl_xor(t, 1);
      t += __shfl_xor(t, 2);
      t += __shfl_xor(t, 4);
      t += __shfl_xor(t, 8);
      lsum[r] = lsum[r] * scl[r] + t;
#pragma unroll
      for (int nt = 0; nt < 4; ++nt) o[nt][r] *= scl[r];
    }
    // P (D-layout) -> LDS row-major bf16 so PV A-frags are contiguous 16B reads
    unsigned short* pl = p_lds[wave];
#pragma unroll
    for (int nt = 0; nt < 4; ++nt)
#pragma unroll
      for (int r = 0; r < 4; ++r)
        pl[(hi * 4 + r) * 72 + nt * 16 + lo] = f32_to_bf16(s[nt][r]);
    asm volatile("s_waitcnt lgkmcnt(0)" ::: "memory");
    __builtin_amdgcn_sched_barrier(0);
    // O += P V   (B-fragment = rows of Vt => contiguous j)
#pragma unroll
    for (int c = 0; c < 2; ++c) {
      ushort8 pf = *(const ushort8*)(pl + lo * 72 + c * 32 + hi * 8);
#pragma unroll
      for (int nt = 0; nt < 4; ++nt) {
        ushort8 vf = *(const ushort8*)(Vt + ((size_t)(b * H_ + nt * 16 + lo) << 11) +
                                       j0 + c * 32 + hi * 8);
        o[nt] = mfma16(pf, vf, o[nt]);
      }
    }
  }

  // epilogue: out = O / lsum (fp32)
#pragma unroll
  for (int r = 0; r < 4; ++r) {
    const float inv = 1.0f / lsum[r];
#pragma unroll
    for (int nt = 0; nt < 4; ++nt)
      out[(bt + i0 + hi * 4 + r) * H_ + nt * 16 + lo] = o[nt][r] * inv;
  }
}

extern "C" void kernel_launch(void* const* d_in, const int* in_sizes, int n_in,
                              void* d_out, int out_size, void* d_ws, size_t ws_size,
                              hipStream_t stream) {
  const float* x = (const float*)d_in[0];
  const float* Wk = (const float*)d_in[1];
  const float* Wq = (const float*)d_in[2];
  const float* Wv = (const float*)d_in[3];
  float* out = (float*)d_out;

  char* ws = (char*)d_ws;
  unsigned short* Qb = (unsigned short*)(ws);                  // 2 MB  [B*T][64] bf16
  unsigned short* Kb = (unsigned short*)(ws + (2u << 20));     // 2 MB  [B*T][64] bf16
  unsigned short* Vt = (unsigned short*)(ws + (4u << 20));     // 2 MB  [B][64][T] bf16
  unsigned short* Wt = (unsigned short*)(ws + (6u << 20));     // 288KB [3][64][768] bf16

  prep_w_kernel<<<dim3((3 * C_ * H_ + 255) / 256), dim3(256), 0, stream>>>(Wk, Wq, Wv, Wt);
  proj_kernel<<<dim3((B_ * T_) / 64), dim3(256), 0, stream>>>(x, Wt, Qb, Kb, Vt);
  attn_kernel<<<dim3(T_ / 64, B_), dim3(256), 0, stream>>>(Qb, Kb, Vt, out);
}

// Round 2
// 117.175 us; speedup vs baseline: 1.5161x; 1.5161x over previous
//
#include <hip/hip_runtime.h>

#define B_ 8
#define T_ 2048
#define C_ 768
#define H_ 64

typedef __bf16 bf16x8 __attribute__((ext_vector_type(8)));
typedef unsigned short ushort8 __attribute__((ext_vector_type(8)));
typedef float f32x4 __attribute__((ext_vector_type(4)));

typedef __attribute__((address_space(1))) const void g_void;
typedef __attribute__((address_space(3))) void lds_void;

static __device__ __forceinline__ unsigned short f32_to_bf16(float f) {
  unsigned int u = __float_as_uint(f);
  u += 0x7FFFu + ((u >> 16) & 1u);
  return (unsigned short)(u >> 16);
}

static __device__ __forceinline__ f32x4 mfma16(ushort8 a, ushort8 b, f32x4 c) {
  return __builtin_amdgcn_mfma_f32_16x16x32_bf16(
      __builtin_bit_cast(bf16x8, a), __builtin_bit_cast(bf16x8, b), c, 0, 0, 0);
}

// ---------------- Kernel 0: W -> Wt (bf16, transposed [3][64][768]) ------------------
// Wq pre-scaled by head_size^-0.5 * log2(e) so softmax can use raw exp2.
__global__ void prep_w_kernel(const float* __restrict__ Wk, const float* __restrict__ Wq,
                              const float* __restrict__ Wv, unsigned short* __restrict__ Wt) {
  int idx = blockIdx.x * 256 + threadIdx.x;
  if (idx >= 3 * C_ * H_) return;
  int p = idx / (C_ * H_);
  int rem = idx - p * (C_ * H_);
  int k = rem >> 6;
  int n = rem & 63;
  const float* W = (p == 0) ? Wk : (p == 1) ? Wq : Wv;
  float v = W[rem];
  if (p == 1) v *= 0.125f * 1.44269504088896f;  // 1/sqrt(64) * log2(e)
  Wt[p * (H_ * C_) + n * C_ + k] = f32_to_bf16(v);
}

// ---------------- Kernel 1: projections x@W{k,q,v} via MFMA --------------------------
// grid = (B*T)/32 blocks, 256 threads (4 waves).
// wave = (rg, half): rg picks 16-row group, half picks 6 of the 12 (p,nt) tiles.
// => 2048 waves total = 2 waves/SIMD (vs 1 before).
__global__ __launch_bounds__(256) void proj_kernel(
    const float* __restrict__ x, const unsigned short* __restrict__ Wt,
    unsigned short* __restrict__ Qb, unsigned short* __restrict__ Kb,
    unsigned short* __restrict__ Vt) {
  const int tid = threadIdx.x;
  const int wave = tid >> 6;
  const int lane = tid & 63;
  const int lo = lane & 15, hi = lane >> 4;
  const int rg = wave & 1, half = wave >> 1;
  const int row0 = blockIdx.x * 32 + rg * 16;

  f32x4 acc[6];
#pragma unroll
  for (int t = 0; t < 6; ++t) acc[t] = (f32x4){0.f, 0.f, 0.f, 0.f};

  const float* xrow = x + (size_t)(row0 + lo) * C_;
#pragma unroll 2
  for (int kc = 0; kc < C_; kc += 32) {
    const int ko = kc + hi * 8;
    float4 a0 = *(const float4*)(xrow + ko);
    float4 a1 = *(const float4*)(xrow + ko + 4);
    ushort8 a;
    a[0] = f32_to_bf16(a0.x); a[1] = f32_to_bf16(a0.y);
    a[2] = f32_to_bf16(a0.z); a[3] = f32_to_bf16(a0.w);
    a[4] = f32_to_bf16(a1.x); a[5] = f32_to_bf16(a1.y);
    a[6] = f32_to_bf16(a1.z); a[7] = f32_to_bf16(a1.w);
#pragma unroll
    for (int t = 0; t < 6; ++t) {
      const int lt = half * 6 + t;
      const int p = lt >> 2, nt = lt & 3;
      ushort8 bfr = *(const ushort8*)(Wt + p * (H_ * C_) + (nt * 16 + lo) * C_ + ko);
      acc[t] = mfma16(a, bfr, acc[t]);
    }
  }

#pragma unroll
  for (int t = 0; t < 6; ++t) {
    const int lt = half * 6 + t;
    const int p = lt >> 2, nt = lt & 3;
#pragma unroll
    for (int r = 0; r < 4; ++r) {
      const int rgl = row0 + hi * 4 + r;
      const int n = nt * 16 + lo;
      unsigned short val = f32_to_bf16(acc[t][r]);
      if (p == 0) {
        Kb[rgl * H_ + n] = val;
      } else if (p == 1) {
        Qb[rgl * H_ + n] = val;
      } else {
        const int b = rgl >> 11;
        const int tt = rgl & (T_ - 1);
        Vt[((b * H_ + n) << 11) + tt] = val;
      }
    }
  }
}

// ---------------- Kernel 2: causal flash attention -----------------------------------
// grid = (T/64, B), 256 threads (4 waves); wave w owns Q rows [qt*64+w*16, +16).
// K/V tiles double-buffered in LDS via global_load_lds (shared by all 4 waves),
// XOR-swizzled (pre-swizzled global source + swizzled ds_read) to kill the
// 32-way stride-128B bank conflict.
__global__ __launch_bounds__(256) void attn_kernel(
    const unsigned short* __restrict__ Qb, const unsigned short* __restrict__ Kb,
    const unsigned short* __restrict__ Vt, float* __restrict__ out) {
  __shared__ unsigned short Kl[2][64 * 64];   // [j][d8^swz] 8KB each
  __shared__ unsigned short Vl[2][64 * 64];   // [d][j8^swz]
  __shared__ unsigned short p_lds[4][16 * 72];

  const int tid = threadIdx.x;
  const int wave = tid >> 6;
  const int lane = tid & 63;
  const int lo = lane & 15, hi = lane >> 4;
  const int b = blockIdx.y;
  const int qt = blockIdx.x;
  const int i0 = qt * 64 + wave * 16;
  const size_t bt = (size_t)b * T_;
  const int ntiles = qt + 1;

  // staging source indices (same for every tile; only the tile base changes)
  const int srow = tid >> 3;                       // 0..31 row within half-tile
  const int sslot = (tid & 7) ^ (srow & 7);        // swizzled 16B slot
  const int ldsoff = (tid >> 6) * 512;             // wave-uniform ushort offset (1KB/wave)

  // Q fragments (pre-scaled)
  ushort8 qf[2];
  qf[0] = *(const ushort8*)(Qb + (bt + i0 + lo) * H_ + hi * 8);
  qf[1] = *(const ushort8*)(Qb + (bt + i0 + lo) * H_ + 32 + hi * 8);

  f32x4 o[4];
#pragma unroll
  for (int nt = 0; nt < 4; ++nt) o[nt] = (f32x4){0.f, 0.f, 0.f, 0.f};
  float m[4] = {-1e30f, -1e30f, -1e30f, -1e30f};
  float lsum[4] = {0.f, 0.f, 0.f, 0.f};

  // ---- stage tile jt into buffer buf (4 x 4KB issues, 256 threads x 16B each) ----
  auto stage = [&](int buf, int jt) {
    const int j0 = jt * 64;
#pragma unroll
    for (int is = 0; is < 2; ++is) {
      const int j = is * 32 + srow;
      const unsigned short* gK = Kb + ((bt + j0 + j) << 6) + (sslot << 3);
      __builtin_amdgcn_global_load_lds((g_void*)gK,
          (lds_void*)(&Kl[buf][is * 2048 + ldsoff]), 16, 0, 0);
    }
#pragma unroll
    for (int is = 0; is < 2; ++is) {
      const int d = is * 32 + srow;
      const unsigned short* gV = Vt + (((size_t)(b * H_ + d)) << 11) + j0 + (sslot << 3);
      __builtin_amdgcn_global_load_lds((g_void*)gV,
          (lds_void*)(&Vl[buf][is * 2048 + ldsoff]), 16, 0, 0);
    }
  };

  stage(0, 0);

  for (int jt = 0; jt < ntiles; ++jt) {
    const int cur = jt & 1;
    asm volatile("s_waitcnt vmcnt(0)" ::: "memory");
    __syncthreads();  // staged tile visible; previous reads of buf cur^1 done
    if (jt + 1 < ntiles) stage(cur ^ 1, jt + 1);

    // S = Q K^T from LDS (swizzled reads)
    f32x4 s[4];
#pragma unroll
    for (int nt = 0; nt < 4; ++nt) s[nt] = (f32x4){0.f, 0.f, 0.f, 0.f};
#pragma unroll
    for (int c = 0; c < 2; ++c) {
#pragma unroll
      for (int nt = 0; nt < 4; ++nt) {
        const int j = nt * 16 + lo;
        ushort8 kf = *(const ushort8*)(&Kl[cur][(j << 6) + ((((c << 2) + hi) ^ (lo & 7)) << 3)]);
        s[nt] = mfma16(qf[c], kf, s[nt]);
      }
    }
    // causal mask on diagonal tile
    if (jt == qt) {
#pragma unroll
      for (int nt = 0; nt < 4; ++nt)
#pragma unroll
        for (int r = 0; r < 4; ++r)
          if (nt * 16 + lo > wave * 16 + hi * 4 + r) s[nt][r] = -1e30f;
    }
    // online softmax (log2 units, raw exp2)
    float mnew[4], scl[4];
#pragma unroll
    for (int r = 0; r < 4; ++r) {
      float t = fmaxf(fmaxf(s[0][r], s[1][r]), fmaxf(s[2][r], s[3][r]));
      t = fmaxf(t, __shfl_xor(t, 1));
      t = fmaxf(t, __shfl_xor(t, 2));
      t = fmaxf(t, __shfl_xor(t, 4));
      t = fmaxf(t, __shfl_xor(t, 8));
      mnew[r] = fmaxf(m[r], t);
      scl[r] = exp2f(m[r] - mnew[r]);
      m[r] = mnew[r];
    }
    float tsum[4] = {0.f, 0.f, 0.f, 0.f};
#pragma unroll
    for (int nt = 0; nt < 4; ++nt)
#pragma unroll
      for (int r = 0; r < 4; ++r) {
        float p = exp2f(s[nt][r] - mnew[r]);
        s[nt][r] = p;
        tsum[r] += p;
      }
#pragma unroll
    for (int r = 0; r < 4; ++r) {
      float t = tsum[r];
      t += __shfl_xor(t, 1);
      t += __shfl_xor(t, 2);
      t += __shfl_xor(t, 4);
      t += __shfl_xor(t, 8);
      lsum[r] = lsum[r] * scl[r] + t;
#pragma unroll
      for (int nt = 0; nt < 4; ++nt) o[nt][r] *= scl[r];
    }
    // P -> LDS (row-major, pad 72) for A-fragment reads
    unsigned short* pl = p_lds[wave];
#pragma unroll
    for (int nt = 0; nt < 4; ++nt)
#pragma unroll
      for (int r = 0; r < 4; ++r)
        pl[(hi * 4 + r) * 72 + nt * 16 + lo] = f32_to_bf16(s[nt][r]);
    asm volatile("s_waitcnt lgkmcnt(0)" ::: "memory");
    __builtin_amdgcn_sched_barrier(0);
    // O += P V from LDS (swizzled V reads)
#pragma unroll
    for (int c = 0; c < 2; ++c) {
      ushort8 pf = *(const ushort8*)(pl + lo * 72 + c * 32 + hi * 8);
#pragma unroll
      for (int nt = 0; nt < 4; ++nt) {
        const int d = nt * 16 + lo;
        ushort8 vf = *(const ushort8*)(&Vl[cur][(d << 6) + ((((c << 2) + hi) ^ (lo & 7)) << 3)]);
        o[nt] = mfma16(pf, vf, o[nt]);
      }
    }
  }

  // epilogue: out = O / lsum (fp32)
#pragma unroll
  for (int r = 0; r < 4; ++r) {
    const float inv = 1.0f / lsum[r];
#pragma unroll
    for (int nt = 0; nt < 4; ++nt)
      out[(bt + i0 + hi * 4 + r) * H_ + nt * 16 + lo] = o[nt][r] * inv;
  }
}

extern "C" void kernel_launch(void* const* d_in, const int* in_sizes, int n_in,
                              void* d_out, int out_size, void* d_ws, size_t ws_size,
                              hipStream_t stream) {
  const float* x = (const float*)d_in[0];
  const float* Wk = (const float*)d_in[1];
  const float* Wq = (const float*)d_in[2];
  const float* Wv = (const float*)d_in[3];
  float* out = (float*)d_out;

  char* ws = (char*)d_ws;
  unsigned short* Qb = (unsigned short*)(ws);                  // 2 MB  [B*T][64] bf16
  unsigned short* Kb = (unsigned short*)(ws + (2u << 20));     // 2 MB  [B*T][64] bf16
  unsigned short* Vt = (unsigned short*)(ws + (4u << 20));     // 2 MB  [B][64][T] bf16
  unsigned short* Wt = (unsigned short*)(ws + (6u << 20));     // 288KB [3][64][768] bf16

  prep_w_kernel<<<dim3((3 * C_ * H_ + 255) / 256), dim3(256), 0, stream>>>(Wk, Wq, Wv, Wt);
  proj_kernel<<<dim3((B_ * T_) / 32), dim3(256), 0, stream>>>(x, Wt, Qb, Kb, Vt);
  attn_kernel<<<dim3(T_ / 64, B_), dim3(256), 0, stream>>>(Qb, Kb, Vt, out);
}

// Round 3
// 107.896 us; speedup vs baseline: 1.6465x; 1.0860x over previous
//
#include <hip/hip_runtime.h>

#define B_ 8
#define T_ 2048
#define C_ 768
#define H_ 64
#define QT_ (T_ / 64)   // 32 Q-tiles
#define CH_ 8           // j-tiles per chunk
#define NCH_ 4          // max chunks per Q-tile

typedef __bf16 bf16x8 __attribute__((ext_vector_type(8)));
typedef unsigned short ushort8 __attribute__((ext_vector_type(8)));
typedef float f32x4 __attribute__((ext_vector_type(4)));

typedef __attribute__((address_space(1))) const void g_void;
typedef __attribute__((address_space(3))) void lds_void;

static __device__ __forceinline__ unsigned short f32_to_bf16(float f) {
  unsigned int u = __float_as_uint(f);
  u += 0x7FFFu + ((u >> 16) & 1u);
  return (unsigned short)(u >> 16);
}

static __device__ __forceinline__ f32x4 mfma16(ushort8 a, ushort8 b, f32x4 c) {
  return __builtin_amdgcn_mfma_f32_16x16x32_bf16(
      __builtin_bit_cast(bf16x8, a), __builtin_bit_cast(bf16x8, b), c, 0, 0, 0);
}

// ---------------- Kernel 0: W -> Wt (bf16, transposed [3][64][768]) ------------------
// Wq pre-scaled by head_size^-0.5 * log2(e) so softmax can use raw exp2.
__global__ void prep_w_kernel(const float* __restrict__ Wk, const float* __restrict__ Wq,
                              const float* __restrict__ Wv, unsigned short* __restrict__ Wt) {
  int idx = blockIdx.x * 256 + threadIdx.x;
  if (idx >= 3 * C_ * H_) return;
  int p = idx / (C_ * H_);
  int rem = idx - p * (C_ * H_);
  int k = rem >> 6;
  int n = rem & 63;
  const float* W = (p == 0) ? Wk : (p == 1) ? Wq : Wv;
  float v = W[rem];
  if (p == 1) v *= 0.125f * 1.44269504088896f;  // 1/sqrt(64) * log2(e)
  Wt[p * (H_ * C_) + n * C_ + k] = f32_to_bf16(v);
}

// ---------------- Kernel 1: projections x@W{k,q,v} via MFMA --------------------------
// grid = B*T/16 = 1024 blocks, 256 threads (4 waves). All 4 waves share the same
// 16 x-rows (L1-served); wave w computes 3 of the 12 (p,nt) output tiles.
// => 4096 waves = 4 waves/SIMD.
__global__ __launch_bounds__(256) void proj_kernel(
    const float* __restrict__ x, const unsigned short* __restrict__ Wt,
    unsigned short* __restrict__ Qb, unsigned short* __restrict__ Kb,
    unsigned short* __restrict__ Vt) {
  const int tid = threadIdx.x;
  const int wave = tid >> 6;
  const int lane = tid & 63;
  const int lo = lane & 15, hi = lane >> 4;
  const int row0 = blockIdx.x * 16;

  f32x4 acc[3];
#pragma unroll
  for (int t = 0; t < 3; ++t) acc[t] = (f32x4){0.f, 0.f, 0.f, 0.f};

  const float* xrow = x + (size_t)(row0 + lo) * C_;
#pragma unroll 2
  for (int kc = 0; kc < C_; kc += 32) {
    const int ko = kc + hi * 8;
    float4 a0 = *(const float4*)(xrow + ko);
    float4 a1 = *(const float4*)(xrow + ko + 4);
    ushort8 a;
    a[0] = f32_to_bf16(a0.x); a[1] = f32_to_bf16(a0.y);
    a[2] = f32_to_bf16(a0.z); a[3] = f32_to_bf16(a0.w);
    a[4] = f32_to_bf16(a1.x); a[5] = f32_to_bf16(a1.y);
    a[6] = f32_to_bf16(a1.z); a[7] = f32_to_bf16(a1.w);
#pragma unroll
    for (int t = 0; t < 3; ++t) {
      const int lt = wave * 3 + t;
      const int p = lt >> 2, nt = lt & 3;
      ushort8 bfr = *(const ushort8*)(Wt + p * (H_ * C_) + (nt * 16 + lo) * C_ + ko);
      acc[t] = mfma16(a, bfr, acc[t]);
    }
  }

#pragma unroll
  for (int t = 0; t < 3; ++t) {
    const int lt = wave * 3 + t;
    const int p = lt >> 2, nt = lt & 3;
#pragma unroll
    for (int r = 0; r < 4; ++r) {
      const int rgl = row0 + hi * 4 + r;
      const int n = nt * 16 + lo;
      unsigned short val = f32_to_bf16(acc[t][r]);
      if (p == 0) {
        Kb[rgl * H_ + n] = val;
      } else if (p == 1) {
        Qb[rgl * H_ + n] = val;
      } else {
        const int b = rgl >> 11;
        const int tt = rgl & (T_ - 1);
        Vt[((b * H_ + n) << 11) + tt] = val;
      }
    }
  }
}

// ---------------- Kernel 2: causal flash attention, split-j partials -----------------
// grid = (QT_, B, NCH_); block (qt,b,ch) processes j-tiles [ch*8, min(qt, ch*8+7)]
// and emits un-normalized O plus per-row (m, l) in log2 units.
__global__ __launch_bounds__(256) void attn_part_kernel(
    const unsigned short* __restrict__ Qb, const unsigned short* __restrict__ Kb,
    const unsigned short* __restrict__ Vt, float* __restrict__ Op, float* __restrict__ Ml) {
  const int qt = blockIdx.x;
  const int b = blockIdx.y;
  const int ch = blockIdx.z;
  const int t0 = ch * CH_;
  if (t0 > qt) return;
  const int t1 = min(qt, t0 + CH_ - 1);

  __shared__ unsigned short Kl[2][64 * 64];
  __shared__ unsigned short Vl[2][64 * 64];
  __shared__ unsigned short p_lds[4][16 * 72];

  const int tid = threadIdx.x;
  const int wave = tid >> 6;
  const int lane = tid & 63;
  const int lo = lane & 15, hi = lane >> 4;
  const int i0 = qt * 64 + wave * 16;
  const size_t bt = (size_t)b * T_;

  const int srow = tid >> 3;
  const int sslot = (tid & 7) ^ (srow & 7);
  const int ldsoff = (tid >> 6) * 512;

  ushort8 qf[2];
  qf[0] = *(const ushort8*)(Qb + (bt + i0 + lo) * H_ + hi * 8);
  qf[1] = *(const ushort8*)(Qb + (bt + i0 + lo) * H_ + 32 + hi * 8);

  f32x4 o[4];
#pragma unroll
  for (int nt = 0; nt < 4; ++nt) o[nt] = (f32x4){0.f, 0.f, 0.f, 0.f};
  float m[4] = {-1e30f, -1e30f, -1e30f, -1e30f};
  float lsum[4] = {0.f, 0.f, 0.f, 0.f};

  auto stage = [&](int buf, int jt) {
    const int j0 = jt * 64;
#pragma unroll
    for (int is = 0; is < 2; ++is) {
      const int j = is * 32 + srow;
      const unsigned short* gK = Kb + ((bt + j0 + j) << 6) + (sslot << 3);
      __builtin_amdgcn_global_load_lds((g_void*)gK,
          (lds_void*)(&Kl[buf][is * 2048 + ldsoff]), 16, 0, 0);
    }
#pragma unroll
    for (int is = 0; is < 2; ++is) {
      const int d = is * 32 + srow;
      const unsigned short* gV = Vt + (((size_t)(b * H_ + d)) << 11) + j0 + (sslot << 3);
      __builtin_amdgcn_global_load_lds((g_void*)gV,
          (lds_void*)(&Vl[buf][is * 2048 + ldsoff]), 16, 0, 0);
    }
  };

  stage(0, t0);

  for (int jt = t0; jt <= t1; ++jt) {
    const int cur = (jt - t0) & 1;
    asm volatile("s_waitcnt vmcnt(0)" ::: "memory");
    __syncthreads();
    if (jt < t1) stage(cur ^ 1, jt + 1);

    f32x4 s[4];
#pragma unroll
    for (int nt = 0; nt < 4; ++nt) s[nt] = (f32x4){0.f, 0.f, 0.f, 0.f};
#pragma unroll
    for (int c = 0; c < 2; ++c) {
#pragma unroll
      for (int nt = 0; nt < 4; ++nt) {
        const int j = nt * 16 + lo;
        ushort8 kf = *(const ushort8*)(&Kl[cur][(j << 6) + ((((c << 2) + hi) ^ (lo & 7)) << 3)]);
        s[nt] = mfma16(qf[c], kf, s[nt]);
      }
    }
    if (jt == qt) {
#pragma unroll
      for (int nt = 0; nt < 4; ++nt)
#pragma unroll
        for (int r = 0; r < 4; ++r)
          if (nt * 16 + lo > wave * 16 + hi * 4 + r) s[nt][r] = -1e30f;
    }
    float mnew[4], scl[4];
#pragma unroll
    for (int r = 0; r < 4; ++r) {
      float t = fmaxf(fmaxf(s[0][r], s[1][r]), fmaxf(s[2][r], s[3][r]));
      t = fmaxf(t, __shfl_xor(t, 1));
      t = fmaxf(t, __shfl_xor(t, 2));
      t = fmaxf(t, __shfl_xor(t, 4));
      t = fmaxf(t, __shfl_xor(t, 8));
      mnew[r] = fmaxf(m[r], t);
      scl[r] = exp2f(m[r] - mnew[r]);
      m[r] = mnew[r];
    }
    float tsum[4] = {0.f, 0.f, 0.f, 0.f};
#pragma unroll
    for (int nt = 0; nt < 4; ++nt)
#pragma unroll
      for (int r = 0; r < 4; ++r) {
        float p = exp2f(s[nt][r] - mnew[r]);
        s[nt][r] = p;
        tsum[r] += p;
      }
#pragma unroll
    for (int r = 0; r < 4; ++r) {
      float t = tsum[r];
      t += __shfl_xor(t, 1);
      t += __shfl_xor(t, 2);
      t += __shfl_xor(t, 4);
      t += __shfl_xor(t, 8);
      lsum[r] = lsum[r] * scl[r] + t;
#pragma unroll
      for (int nt = 0; nt < 4; ++nt) o[nt][r] *= scl[r];
    }
    unsigned short* pl = p_lds[wave];
#pragma unroll
    for (int nt = 0; nt < 4; ++nt)
#pragma unroll
      for (int r = 0; r < 4; ++r)
        pl[(hi * 4 + r) * 72 + nt * 16 + lo] = f32_to_bf16(s[nt][r]);
    asm volatile("s_waitcnt lgkmcnt(0)" ::: "memory");
    __builtin_amdgcn_sched_barrier(0);
#pragma unroll
    for (int c = 0; c < 2; ++c) {
      ushort8 pf = *(const ushort8*)(pl + lo * 72 + c * 32 + hi * 8);
#pragma unroll
      for (int nt = 0; nt < 4; ++nt) {
        const int d = nt * 16 + lo;
        ushort8 vf = *(const ushort8*)(&Vl[cur][(d << 6) + ((((c << 2) + hi) ^ (lo & 7)) << 3)]);
        o[nt] = mfma16(pf, vf, o[nt]);
      }
    }
  }

  // store partials: un-normalized O, per-row m and l (log2 units)
  const size_t pb = (size_t)(b * QT_ + qt) * NCH_ + ch;
  float* op = Op + pb * 4096;
#pragma unroll
  for (int nt = 0; nt < 4; ++nt)
#pragma unroll
    for (int r = 0; r < 4; ++r)
      op[(wave * 16 + hi * 4 + r) * 64 + nt * 16 + lo] = o[nt][r];
  if (lo == 0) {
    float* ml = Ml + pb * 128;
#pragma unroll
    for (int r = 0; r < 4; ++r) {
      ml[wave * 16 + hi * 4 + r] = m[r];
      ml[64 + wave * 16 + hi * 4 + r] = lsum[r];
    }
  }
}

// ---------------- Kernel 3: combine split-j partials ---------------------------------
// grid = (QT_, B), 256 threads: thread -> (row = tid/4, 16-col group = tid%4)
__global__ __launch_bounds__(256) void attn_comb_kernel(
    const float* __restrict__ Op, const float* __restrict__ Ml, float* __restrict__ out) {
  const int qt = blockIdx.x;
  const int b = blockIdx.y;
  const int nc = (qt >> 3) + 1;  // ceil((qt+1)/CH_)
  const int row = threadIdx.x >> 2;
  const int c0 = (threadIdx.x & 3) * 16;
  const size_t pbase = (size_t)(b * QT_ + qt) * NCH_;

  float mv[NCH_], wv[NCH_];
  float m_g = -1e30f;
  for (int c = 0; c < nc; ++c) {
    mv[c] = Ml[(pbase + c) * 128 + row];
    m_g = fmaxf(m_g, mv[c]);
  }
  float l_g = 0.f;
  for (int c = 0; c < nc; ++c) {
    wv[c] = exp2f(mv[c] - m_g);
    l_g += Ml[(pbase + c) * 128 + 64 + row] * wv[c];
  }
  const float inv = 1.0f / l_g;

  f32x4 a0 = {0,0,0,0}, a1 = {0,0,0,0}, a2 = {0,0,0,0}, a3 = {0,0,0,0};
  for (int c = 0; c < nc; ++c) {
    const float* op = Op + (pbase + c) * 4096 + row * 64 + c0;
    const float wc = wv[c];
    f32x4 v0 = *(const f32x4*)(op);
    f32x4 v1 = *(const f32x4*)(op + 4);
    f32x4 v2 = *(const f32x4*)(op + 8);
    f32x4 v3 = *(const f32x4*)(op + 12);
    a0 += v0 * wc; a1 += v1 * wc; a2 += v2 * wc; a3 += v3 * wc;
  }
  float* o = out + ((size_t)b * T_ + qt * 64 + row) * 64 + c0;
  *(f32x4*)(o) = a0 * inv;
  *(f32x4*)(o + 4) = a1 * inv;
  *(f32x4*)(o + 8) = a2 * inv;
  *(f32x4*)(o + 12) = a3 * inv;
}

extern "C" void kernel_launch(void* const* d_in, const int* in_sizes, int n_in,
                              void* d_out, int out_size, void* d_ws, size_t ws_size,
                              hipStream_t stream) {
  const float* x = (const float*)d_in[0];
  const float* Wk = (const float*)d_in[1];
  const float* Wq = (const float*)d_in[2];
  const float* Wv = (const float*)d_in[3];
  float* out = (float*)d_out;

  char* ws = (char*)d_ws;
  unsigned short* Qb = (unsigned short*)(ws);                  // 2 MB   [B*T][64] bf16
  unsigned short* Kb = (unsigned short*)(ws + (2u << 20));     // 2 MB   [B*T][64] bf16
  unsigned short* Vt = (unsigned short*)(ws + (4u << 20));     // 2 MB   [B][64][T] bf16
  unsigned short* Wt = (unsigned short*)(ws + (6u << 20));     // 288 KB [3][64][768] bf16
  float* Op = (float*)(ws + (8u << 20));                       // 16 MB  [B][32][4][64][64] f32
  float* Ml = (float*)(ws + (24u << 20));                      // 512 KB [B][32][4][2][64] f32

  prep_w_kernel<<<dim3((3 * C_ * H_ + 255) / 256), dim3(256), 0, stream>>>(Wk, Wq, Wv, Wt);
  proj_kernel<<<dim3((B_ * T_) / 16), dim3(256), 0, stream>>>(x, Wt, Qb, Kb, Vt);
  attn_part_kernel<<<dim3(QT_, B_, NCH_), dim3(256), 0, stream>>>(Qb, Kb, Vt, Op, Ml);
  attn_comb_kernel<<<dim3(QT_, B_), dim3(256), 0, stream>>>(Op, Ml, out);
}

// Round 4
// 71.799 us; speedup vs baseline: 2.4743x; 1.5028x over previous
//
#include <hip/hip_runtime.h>

#define B_ 8
#define T_ 2048
#define C_ 768
#define H_ 64
#define QT_ (T_ / 64)   // 32 Q-tiles
#define CH_ 8           // j-tiles per chunk
#define NCH_ 4          // max chunks per Q-tile

typedef __bf16 bf16x8 __attribute__((ext_vector_type(8)));
typedef unsigned short ushort8 __attribute__((ext_vector_type(8)));
typedef float f32x4 __attribute__((ext_vector_type(4)));

typedef __attribute__((address_space(1))) const void g_void;
typedef __attribute__((address_space(3))) void lds_void;

static __device__ __forceinline__ unsigned short f32_to_bf16(float f) {
  unsigned int u = __float_as_uint(f);
  u += 0x7FFFu + ((u >> 16) & 1u);
  return (unsigned short)(u >> 16);
}

static __device__ __forceinline__ unsigned int cvtpk_bf16(float a, float b) {
  unsigned int r;
  asm("v_cvt_pk_bf16_f32 %0, %1, %2" : "=v"(r) : "v"(a), "v"(b));
  return r;
}

static __device__ __forceinline__ f32x4 mfma16(ushort8 a, ushort8 b, f32x4 c) {
  return __builtin_amdgcn_mfma_f32_16x16x32_bf16(
      __builtin_bit_cast(bf16x8, a), __builtin_bit_cast(bf16x8, b), c, 0, 0, 0);
}

// ---------------- Kernel 0: W -> Wt in PRE-SWIZZLED per-K-step tiled layout ----------
// Layout: 24 K-steps x 768 slots of 16B. Slot s within a step holds col n = s>>2,
// k8 = (s&3) ^ (n&3) ^ ((n>>2)&3)  (XOR involution => conflict-free ds_read_b128 and
// linear global_load_lds staging). n in [0,192): p = n>>6 (K,Q,V), col = n&63.
// Wq pre-scaled by head_size^-0.5 * log2(e) so softmax uses raw exp2.
__global__ void prep_w_kernel(const float* __restrict__ Wk, const float* __restrict__ Wq,
                              const float* __restrict__ Wv, unsigned short* __restrict__ Wt) {
  int g = blockIdx.x * 256 + threadIdx.x;
  if (g >= 24 * 768) return;
  int ks = g / 768, s = g - ks * 768;
  int n = s >> 2, perm = s & 3;
  int k8 = perm ^ (n & 3) ^ ((n >> 2) & 3);
  int p = n >> 6, col = n & 63;
  const float* W = (p == 0) ? Wk : (p == 1) ? Wq : Wv;
  float sc = (p == 1) ? 0.125f * 1.44269504088896f : 1.0f;
  int kbase = ks * 32 + k8 * 8;
  ushort8 v;
#pragma unroll
  for (int e = 0; e < 8; ++e) v[e] = f32_to_bf16(W[(kbase + e) * 64 + col] * sc);
  *(ushort8*)(Wt + (size_t)g * 8) = v;
}

// ---------------- Kernel 1: projections as LDS-staged pipelined GEMM -----------------
// grid = (B*T)/32 = 512 blocks (2/CU), 256 threads (4 waves).
// Wave w owns rows [(w&1)*16, +16) x cols [(w>>1)*96, +96) => 6 MFMA tiles, acc[6].
// Per K-step (32): Wt tile (12KB) staged linearly via global_load_lds (pre-swizzled
// global layout); x tile (32x32 fp32 -> bf16, 2KB) reg-staged + cvt_pk + swizzled
// ds_write. Both double-buffered, prefetched 1 step ahead.
__global__ __launch_bounds__(256) void proj_kernel(
    const float* __restrict__ x, const unsigned short* __restrict__ Wt,
    unsigned short* __restrict__ Qb, unsigned short* __restrict__ Kb,
    unsigned short* __restrict__ Vt) {
  __shared__ unsigned short Wl[2][6144];  // 12KB per buffer
  __shared__ unsigned short Xl[2][1024];  // 2KB per buffer
  const int tid = threadIdx.x;
  const int wave = tid >> 6, lane = tid & 63;
  const int lo = lane & 15, hi = lane >> 4;
  const int rg = wave & 1, ch2 = wave >> 1;
  const int row0 = blockIdx.x * 32;

  f32x4 acc[6];
#pragma unroll
  for (int t = 0; t < 6; ++t) acc[t] = (f32x4){0.f, 0.f, 0.f, 0.f};

  // x staging mapping (threads 0..127): row = tid>>2, k8 = tid&3
  const int xr = (tid & 127) >> 2;
  const int xk8 = tid & 3;
  const int xslot = xr * 4 + (xk8 ^ (xr & 3) ^ ((xr >> 2) & 3));
  const float* xsrc = x + (size_t)(row0 + xr) * C_ + xk8 * 8;

  // A-fragment read address (swizzled)
  const int arow = rg * 16 + lo;
  const int aaddr = (arow * 4 + (hi ^ (arow & 3) ^ ((arow >> 2) & 3))) * 8;

  auto wstage = [&](int buf, int ks) {
    const unsigned short* src = Wt + (size_t)ks * 6144 + tid * 8;
#pragma unroll
    for (int is = 0; is < 3; ++is)
      __builtin_amdgcn_global_load_lds((g_void*)(src + is * 2048),
          (lds_void*)(&Wl[buf][is * 2048 + wave * 512]), 16, 0, 0);
  };

  float4 xa0 = {}, xa1 = {}, xb0 = {}, xb1 = {};

  wstage(0, 0);
  if (tid < 128) {
    xa0 = *(const float4*)(xsrc);
    xa1 = *(const float4*)(xsrc + 4);
  }

  for (int ks = 0; ks < 24; ++ks) {
    const int cur = ks & 1;
    asm volatile("s_waitcnt vmcnt(0)" ::: "memory");
    __syncthreads();  // Wt[cur] staged; prior reads of buf cur^1 complete
    if (ks + 1 < 24) {
      wstage(cur ^ 1, ks + 1);
      if (tid < 128) {
        xb0 = *(const float4*)(xsrc + (ks + 1) * 32);
        xb1 = *(const float4*)(xsrc + (ks + 1) * 32 + 4);
      }
    }
    if (tid < 128) {
      unsigned int dd[4];
      dd[0] = cvtpk_bf16(xa0.x, xa0.y);
      dd[1] = cvtpk_bf16(xa0.z, xa0.w);
      dd[2] = cvtpk_bf16(xa1.x, xa1.y);
      dd[3] = cvtpk_bf16(xa1.z, xa1.w);
      *(uint4*)(&Xl[cur][xslot * 8]) = *(uint4*)dd;
    }
    __syncthreads();  // Xl[cur] ready
    ushort8 af = *(const ushort8*)(&Xl[cur][aaddr]);
#pragma unroll
    for (int t = 0; t < 6; ++t) {
      const int n = ch2 * 96 + t * 16 + lo;
      const int baddr = (n * 4 + (hi ^ (n & 3) ^ ((n >> 2) & 3))) * 8;
      ushort8 bfr = *(const ushort8*)(&Wl[cur][baddr]);
      acc[t] = mfma16(af, bfr, acc[t]);
    }
    xa0 = xb0; xa1 = xb1;
  }

  // epilogue: D row = hi*4+r, col = lo (within tile)
#pragma unroll
  for (int t = 0; t < 6; ++t) {
    const int n = ch2 * 96 + t * 16 + lo;
    const int p = n >> 6, nn = n & 63;
#pragma unroll
    for (int r = 0; r < 4; ++r) {
      const int rgl = row0 + rg * 16 + hi * 4 + r;
      unsigned short val = f32_to_bf16(acc[t][r]);
      if (p == 0) {
        Kb[rgl * H_ + nn] = val;
      } else if (p == 1) {
        Qb[rgl * H_ + nn] = val;
      } else {
        const int b = rgl >> 11;
        const int tt = rgl & (T_ - 1);
        Vt[((b * H_ + nn) << 11) + tt] = val;
      }
    }
  }
}

// ---------------- Kernel 2: causal flash attention, split-j partials -----------------
// grid = (QT_, B, NCH_); block (qt,b,ch) processes j-tiles [ch*8, min(qt, ch*8+7)]
// and emits un-normalized O plus per-row (m, l) in log2 units.
__global__ __launch_bounds__(256) void attn_part_kernel(
    const unsigned short* __restrict__ Qb, const unsigned short* __restrict__ Kb,
    const unsigned short* __restrict__ Vt, float* __restrict__ Op, float* __restrict__ Ml) {
  const int qt = blockIdx.x;
  const int b = blockIdx.y;
  const int ch = blockIdx.z;
  const int t0 = ch * CH_;
  if (t0 > qt) return;
  const int t1 = min(qt, t0 + CH_ - 1);

  __shared__ unsigned short Kl[2][64 * 64];
  __shared__ unsigned short Vl[2][64 * 64];
  __shared__ unsigned short p_lds[4][16 * 72];

  const int tid = threadIdx.x;
  const int wave = tid >> 6;
  const int lane = tid & 63;
  const int lo = lane & 15, hi = lane >> 4;
  const int i0 = qt * 64 + wave * 16;
  const size_t bt = (size_t)b * T_;

  const int srow = tid >> 3;
  const int sslot = (tid & 7) ^ (srow & 7);
  const int ldsoff = (tid >> 6) * 512;

  ushort8 qf[2];
  qf[0] = *(const ushort8*)(Qb + (bt + i0 + lo) * H_ + hi * 8);
  qf[1] = *(const ushort8*)(Qb + (bt + i0 + lo) * H_ + 32 + hi * 8);

  f32x4 o[4];
#pragma unroll
  for (int nt = 0; nt < 4; ++nt) o[nt] = (f32x4){0.f, 0.f, 0.f, 0.f};
  float m[4] = {-1e30f, -1e30f, -1e30f, -1e30f};
  float lsum[4] = {0.f, 0.f, 0.f, 0.f};

  auto stage = [&](int buf, int jt) {
    const int j0 = jt * 64;
#pragma unroll
    for (int is = 0; is < 2; ++is) {
      const int j = is * 32 + srow;
      const unsigned short* gK = Kb + ((bt + j0 + j) << 6) + (sslot << 3);
      __builtin_amdgcn_global_load_lds((g_void*)gK,
          (lds_void*)(&Kl[buf][is * 2048 + ldsoff]), 16, 0, 0);
    }
#pragma unroll
    for (int is = 0; is < 2; ++is) {
      const int d = is * 32 + srow;
      const unsigned short* gV = Vt + (((size_t)(b * H_ + d)) << 11) + j0 + (sslot << 3);
      __builtin_amdgcn_global_load_lds((g_void*)gV,
          (lds_void*)(&Vl[buf][is * 2048 + ldsoff]), 16, 0, 0);
    }
  };

  stage(0, t0);

  for (int jt = t0; jt <= t1; ++jt) {
    const int cur = (jt - t0) & 1;
    asm volatile("s_waitcnt vmcnt(0)" ::: "memory");
    __syncthreads();
    if (jt < t1) stage(cur ^ 1, jt + 1);

    f32x4 s[4];
#pragma unroll
    for (int nt = 0; nt < 4; ++nt) s[nt] = (f32x4){0.f, 0.f, 0.f, 0.f};
#pragma unroll
    for (int c = 0; c < 2; ++c) {
#pragma unroll
      for (int nt = 0; nt < 4; ++nt) {
        const int j = nt * 16 + lo;
        ushort8 kf = *(const ushort8*)(&Kl[cur][(j << 6) + ((((c << 2) + hi) ^ (lo & 7)) << 3)]);
        s[nt] = mfma16(qf[c], kf, s[nt]);
      }
    }
    if (jt == qt) {
#pragma unroll
      for (int nt = 0; nt < 4; ++nt)
#pragma unroll
        for (int r = 0; r < 4; ++r)
          if (nt * 16 + lo > wave * 16 + hi * 4 + r) s[nt][r] = -1e30f;
    }
    float mnew[4], scl[4];
#pragma unroll
    for (int r = 0; r < 4; ++r) {
      float t = fmaxf(fmaxf(s[0][r], s[1][r]), fmaxf(s[2][r], s[3][r]));
      t = fmaxf(t, __shfl_xor(t, 1));
      t = fmaxf(t, __shfl_xor(t, 2));
      t = fmaxf(t, __shfl_xor(t, 4));
      t = fmaxf(t, __shfl_xor(t, 8));
      mnew[r] = fmaxf(m[r], t);
      scl[r] = exp2f(m[r] - mnew[r]);
      m[r] = mnew[r];
    }
    float tsum[4] = {0.f, 0.f, 0.f, 0.f};
#pragma unroll
    for (int nt = 0; nt < 4; ++nt)
#pragma unroll
      for (int r = 0; r < 4; ++r) {
        float p = exp2f(s[nt][r] - mnew[r]);
        s[nt][r] = p;
        tsum[r] += p;
      }
#pragma unroll
    for (int r = 0; r < 4; ++r) {
      float t = tsum[r];
      t += __shfl_xor(t, 1);
      t += __shfl_xor(t, 2);
      t += __shfl_xor(t, 4);
      t += __shfl_xor(t, 8);
      lsum[r] = lsum[r] * scl[r] + t;
#pragma unroll
      for (int nt = 0; nt < 4; ++nt) o[nt][r] *= scl[r];
    }
    unsigned short* pl = p_lds[wave];
#pragma unroll
    for (int nt = 0; nt < 4; ++nt)
#pragma unroll
      for (int r = 0; r < 4; ++r)
        pl[(hi * 4 + r) * 72 + nt * 16 + lo] = f32_to_bf16(s[nt][r]);
    asm volatile("s_waitcnt lgkmcnt(0)" ::: "memory");
    __builtin_amdgcn_sched_barrier(0);
#pragma unroll
    for (int c = 0; c < 2; ++c) {
      ushort8 pf = *(const ushort8*)(pl + lo * 72 + c * 32 + hi * 8);
#pragma unroll
      for (int nt = 0; nt < 4; ++nt) {
        const int d = nt * 16 + lo;
        ushort8 vf = *(const ushort8*)(&Vl[cur][(d << 6) + ((((c << 2) + hi) ^ (lo & 7)) << 3)]);
        o[nt] = mfma16(pf, vf, o[nt]);
      }
    }
  }

  // store partials: un-normalized O, per-row m and l (log2 units)
  const size_t pb = (size_t)(b * QT_ + qt) * NCH_ + ch;
  float* op = Op + pb * 4096;
#pragma unroll
  for (int nt = 0; nt < 4; ++nt)
#pragma unroll
    for (int r = 0; r < 4; ++r)
      op[(wave * 16 + hi * 4 + r) * 64 + nt * 16 + lo] = o[nt][r];
  if (lo == 0) {
    float* ml = Ml + pb * 128;
#pragma unroll
    for (int r = 0; r < 4; ++r) {
      ml[wave * 16 + hi * 4 + r] = m[r];
      ml[64 + wave * 16 + hi * 4 + r] = lsum[r];
    }
  }
}

// ---------------- Kernel 3: combine split-j partials ---------------------------------
__global__ __launch_bounds__(256) void attn_comb_kernel(
    const float* __restrict__ Op, const float* __restrict__ Ml, float* __restrict__ out) {
  const int qt = blockIdx.x;
  const int b = blockIdx.y;
  const int nc = (qt >> 3) + 1;
  const int row = threadIdx.x >> 2;
  const int c0 = (threadIdx.x & 3) * 16;
  const size_t pbase = (size_t)(b * QT_ + qt) * NCH_;

  float mv[NCH_], wv[NCH_];
  float m_g = -1e30f;
  for (int c = 0; c < nc; ++c) {
    mv[c] = Ml[(pbase + c) * 128 + row];
    m_g = fmaxf(m_g, mv[c]);
  }
  float l_g = 0.f;
  for (int c = 0; c < nc; ++c) {
    wv[c] = exp2f(mv[c] - m_g);
    l_g += Ml[(pbase + c) * 128 + 64 + row] * wv[c];
  }
  const float inv = 1.0f / l_g;

  f32x4 a0 = {0,0,0,0}, a1 = {0,0,0,0}, a2 = {0,0,0,0}, a3 = {0,0,0,0};
  for (int c = 0; c < nc; ++c) {
    const float* op = Op + (pbase + c) * 4096 + row * 64 + c0;
    const float wc = wv[c];
    f32x4 v0 = *(const f32x4*)(op);
    f32x4 v1 = *(const f32x4*)(op + 4);
    f32x4 v2 = *(const f32x4*)(op + 8);
    f32x4 v3 = *(const f32x4*)(op + 12);
    a0 += v0 * wc; a1 += v1 * wc; a2 += v2 * wc; a3 += v3 * wc;
  }
  float* o = out + ((size_t)b * T_ + qt * 64 + row) * 64 + c0;
  *(f32x4*)(o) = a0 * inv;
  *(f32x4*)(o + 4) = a1 * inv;
  *(f32x4*)(o + 8) = a2 * inv;
  *(f32x4*)(o + 12) = a3 * inv;
}

extern "C" void kernel_launch(void* const* d_in, const int* in_sizes, int n_in,
                              void* d_out, int out_size, void* d_ws, size_t ws_size,
                              hipStream_t stream) {
  const float* x = (const float*)d_in[0];
  const float* Wk = (const float*)d_in[1];
  const float* Wq = (const float*)d_in[2];
  const float* Wv = (const float*)d_in[3];
  float* out = (float*)d_out;

  char* ws = (char*)d_ws;
  unsigned short* Qb = (unsigned short*)(ws);                  // 2 MB   [B*T][64] bf16
  unsigned short* Kb = (unsigned short*)(ws + (2u << 20));     // 2 MB   [B*T][64] bf16
  unsigned short* Vt = (unsigned short*)(ws + (4u << 20));     // 2 MB   [B][64][T] bf16
  unsigned short* Wt = (unsigned short*)(ws + (6u << 20));     // 288 KB swizzled [24][768]x16B
  float* Op = (float*)(ws + (8u << 20));                       // 16 MB  [B][32][4][64][64] f32
  float* Ml = (float*)(ws + (24u << 20));                      // 512 KB [B][32][4][2][64] f32

  prep_w_kernel<<<dim3(72), dim3(256), 0, stream>>>(Wk, Wq, Wv, Wt);
  proj_kernel<<<dim3((B_ * T_) / 32), dim3(256), 0, stream>>>(x, Wt, Qb, Kb, Vt);
  attn_part_kernel<<<dim3(QT_, B_, NCH_), dim3(256), 0, stream>>>(Qb, Kb, Vt, Op, Ml);
  attn_comb_kernel<<<dim3(QT_, B_), dim3(256), 0, stream>>>(Op, Ml, out);
}